// Round 3
// baseline (155.429 us; speedup 1.0000x reference)
//
#include <hip/hip_runtime.h>

#define BN 64
#define TN 1024
#define VN 1024
#define UNITSN 512
#define TWO_PI 6.283185307179586476925286766559f

// K1: s[b*1024+tau] = sum_v x[b, tau, v].  One wave (64 lanes) per row of 1024 floats.
__global__ void k_reduce_v(const float* __restrict__ x, float* __restrict__ s) {
    int row  = blockIdx.x * 4 + (threadIdx.x >> 6);   // 4 waves per 256-thread block
    int lane = threadIdx.x & 63;
    const float4* xr = reinterpret_cast<const float4*>(x) + (size_t)row * (VN / 4);
    float acc = 0.f;
#pragma unroll
    for (int i = 0; i < 4; ++i) {
        float4 v = xr[i * 64 + lane];                 // consecutive lanes -> consecutive 16B
        acc += (v.x + v.y) + (v.z + v.w);
    }
#pragma unroll
    for (int off = 32; off > 0; off >>= 1)
        acc += __shfl_down(acc, off, 64);
    if (lane == 0) s[row] = acc;
}

// KM: fused middle.  W[b,t] = (1/2048) * sum_tau g[b,tau] * w^(tau*t),  w = e^{-2pi i/1024}
// where g[b,tau] = sum_k (Br[b,k] + i Bi[b,k]) * s[k,tau].
// (Reordered from Bm @ rDFT(s): exact same sums by linearity.)
// Block = (b, t-chunk of 64).  Phase A: g into LDS.  Phase B: register-rotation DFT,
// twiddle re-seeded exactly by sincosf every 64 steps (bounds drift).
__global__ void k_mid(const float* __restrict__ s, const float* __restrict__ Br,
                      const float* __restrict__ Bi, float2* __restrict__ W) {
    __shared__ float2 g[1024];
    __shared__ float2 part[256];

    int b     = blockIdx.x >> 3;
    int tbase = (blockIdx.x & 7) << 6;
    int tid   = threadIdx.x;

    // ---- Phase A: g[tau] for tau = tid, tid+256, tid+512, tid+768
    const float* brp = Br + b * 64;
    const float* bip = Bi + b * 64;
    float gr0 = 0.f, gr1 = 0.f, gr2 = 0.f, gr3 = 0.f;
    float gi0 = 0.f, gi1 = 0.f, gi2 = 0.f, gi3 = 0.f;
#pragma unroll 4
    for (int k = 0; k < 64; ++k) {
        float br = brp[k];                 // uniform -> scalar load
        float bi = bip[k];
        const float* sk = s + k * TN + tid;
        float s0 = sk[0], s1v = sk[256], s2 = sk[512], s3 = sk[768];  // coalesced
        gr0 = fmaf(br, s0, gr0);  gi0 = fmaf(bi, s0, gi0);
        gr1 = fmaf(br, s1v, gr1); gi1 = fmaf(bi, s1v, gi1);
        gr2 = fmaf(br, s2, gr2);  gi2 = fmaf(bi, s2, gi2);
        gr3 = fmaf(br, s3, gr3);  gi3 = fmaf(bi, s3, gi3);
    }
    g[tid]       = make_float2(gr0, gi0);
    g[tid + 256] = make_float2(gr1, gi1);
    g[tid + 512] = make_float2(gr2, gi2);
    g[tid + 768] = make_float2(gr3, gi3);
    __syncthreads();

    // ---- Phase B: 4 threads per t; thread covers tau = tau0 + 4*step, 256 steps.
    int t    = tbase + (tid >> 2);
    int tau0 = tid & 3;

    int pstep = (4 * t) & 1023;            // rotation step = w^(4t)
    float c1, s1;
    sincosf((-TWO_PI / 1024.0f) * (float)pstep, &s1, &c1);   // s1=sin(-th), c1=cos

    float wr = 0.f, wi = 0.f;
#pragma unroll
    for (int g64 = 0; g64 < 4; ++g64) {
        int p0 = ((tau0 + 256 * g64) * t) & 1023;            // exact re-seed
        float cr, ci;
        sincosf((-TWO_PI / 1024.0f) * (float)p0, &ci, &cr);  // ci=sin(-th), cr=cos
        int tau = tau0 + 4 * (g64 * 64);
        for (int u = 0; u < 64; ++u) {
            float2 gv = g[tau];            // 4 distinct addrs/step -> broadcast, no conflict
            wr = fmaf(gv.x, cr, wr); wr = fmaf(-gv.y, ci, wr);
            wi = fmaf(gv.x, ci, wi); wi = fmaf(gv.y, cr, wi);
            float nr = cr * c1 - ci * s1;  // rotate twiddle by w^(4t)
            float nc = cr * s1 + ci * c1;
            cr = nr; ci = nc;
            tau += 4;
        }
    }
    part[tid] = make_float2(wr, wi);
    __syncthreads();

    if (tid < 64) {
        float2 a = part[4 * tid], b2 = part[4 * tid + 1];
        float2 c = part[4 * tid + 2], d = part[4 * tid + 3];
        const float coef = 1.0f / 2048.0f;
        W[b * UNITSN + tbase + tid] =
            make_float2(((a.x + b2.x) + (c.x + d.x)) * coef,
                        ((a.y + b2.y) + (c.y + d.y)) * coef);
    }
}

// K4: out[b][j][t][{re,im}] = W[b,t] + (t+j-511 >= 0 ? W[b, t+j-511] : 0)
// One thread writes 2 consecutive t's as a float4.
__global__ void k_expand(const float2* __restrict__ W, float4* __restrict__ out) {
    int idx = blockIdx.x * 256 + threadIdx.x;         // 64*512*256 total
    int t2 = (idx & 255) * 2;
    int j  = (idx >> 8) & 511;
    int b  = idx >> 17;
    const float2* Wb = W + b * UNITSN;
    float4 w01 = *reinterpret_cast<const float4*>(Wb + t2);  // W[t2], W[t2+1]
    int k0 = t2 + j - 511;
    float2 z0 = (k0 >= 0)     ? Wb[k0]     : make_float2(0.f, 0.f);
    float2 z1 = (k0 + 1 >= 0) ? Wb[k0 + 1] : make_float2(0.f, 0.f);
    out[idx] = make_float4(w01.x + z0.x, w01.y + z0.y, w01.z + z1.x, w01.w + z1.y);
}

extern "C" void kernel_launch(void* const* d_in, const int* in_sizes, int n_in,
                              void* d_out, int out_size, void* d_ws, size_t ws_size,
                              hipStream_t stream) {
    const float* x  = (const float*)d_in[0];
    // d_in[1], d_in[2] (A_r, A_i) are provably unused: the shift-register state's
    // column 0 stays zero for all 512 scan steps.
    const float* Br = (const float*)d_in[3];
    const float* Bi = (const float*)d_in[4];

    char* ws = (char*)d_ws;
    float*  s = (float*)ws;                       // 64*1024 f32 = 256 KB
    float2* W = (float2*)(ws + (64 * 1024 * 4));  // 64*512 cplx = 256 KB

    // K1: 65536 rows, 4 rows/block
    k_reduce_v<<<BN * TN / 4, 256, 0, stream>>>(x, s);
    // KM: 64 b * 8 t-chunks
    k_mid<<<BN * 8, 256, 0, stream>>>(s, Br, Bi, W);
    // K4: 64*512*256 threads
    k_expand<<<(BN * UNITSN * (UNITSN / 2)) / 256, 256, 0, stream>>>(W, (float4*)d_out);
}